// Round 8
// baseline (833.048 us; speedup 1.0000x reference)
//
#include <hip/hip_runtime.h>

#define TPB 256
#define L2E 1.44269504f

typedef float f32x4 __attribute__((ext_vector_type(4)));
typedef short s16x8 __attribute__((ext_vector_type(8)));

// lane->lane XOR shuffle within 32-lane halves (BitMode: xor<<10 | and 0x1F)
#define SWZ(v, m) __int_as_float(__builtin_amdgcn_ds_swizzle(__float_as_int(v), ((m) << 10) | 31))

// DPP cross-lane (VALU): quad_perm xor1/2/3, row_half_mirror = xor7 (within 8)
#define DPP_X1 0xB1
#define DPP_X2 0x4E
#define DPP_X3 0x1B
#define DPP_X7 0x141
template<int CTRL>
__device__ __forceinline__ float DPPX(float v) {
    int i = __float_as_int(v);
    return __int_as_float(__builtin_amdgcn_update_dpp(i, i, CTRL, 0xF, 0xF, false));
}

// exact two-term bf16 split packed into one u32: low16 = hi-part (even k), high16 = lo-part (odd k)
__device__ __forceinline__ unsigned pack_split(float v) {
    unsigned b  = __float_as_uint(v);
    unsigned hi = b >> 16;
    float    hf = __uint_as_float(b & 0xFFFF0000u);
    unsigned lob = __float_as_uint(v - hf) & 0xFFFF0000u;
    return lob | hi;
}

// X LDS layout: [t(10)][el(32)][16 words], col XOR-swizzled by ((el&3)<<2) in 4-word chunks
#define XIDX(t, e, col) ((((t) * 32 + (e)) << 4) | ((col) ^ (((e) & 3) << 2)))

// ---------------- prep kernel: build all segment weights once into d_ws ----------------
__global__ void prep_kernel(const float* __restrict__ Wih0,
                            const float* __restrict__ Wih_rest,
                            const float* __restrict__ Whh,
                            const float* __restrict__ bW,
                            unsigned* __restrict__ wsBF,
                            float* __restrict__ wsWH,
                            float* __restrict__ wsBIAS)
{
    const int tid = threadIdx.x;
    for (int seg = 0; seg < 6; ++seg) {
        const int l = seg >> 1, dir = seg & 1;
        {   // B-fragments: frag = nt*2+part; value = dup16(hi/lo of W_scaled[u][d])
            const int lane_ = tid & 63, part = (tid >> 6) & 1, nt = tid >> 7;
            const int u = nt * 16 + (lane_ & 15);
            const float sc = ((u >> 3) == 2) ? (-2.0f * L2E) : (-L2E);
            #pragma unroll
            for (int ip = 0; ip < 4; ++ip) {
                const int d = (lane_ >> 4) * 4 + ip;
                float w;
                if (l == 0) w = (d < 15) ? Wih0[dir * 480 + u * 15 + d] : 0.0f;
                else        w = Wih_rest[((l - 1) * 2 + dir) * 512 + u * 16 + d];
                w *= sc;
                unsigned b = __float_as_uint(w);
                unsigned v16;
                if (part == 0) v16 = b >> 16;
                else {
                    float hf = __uint_as_float(b & 0xFFFF0000u);
                    v16 = __float_as_uint(w - hf) >> 16;
                }
                wsBF[seg * 4096 + ((nt * 2 + part) * 64 + lane_) * 4 + ip] = v16 | (v16 << 16);
            }
        }
        {   // recurrent weights, pre-permuted for XOR exchange: wh[j][g*8+m] = s_g*Whh[g*8+j][j^m]
            const int jj = tid >> 5, rr = tid & 31, g = rr >> 3, m = rr & 7;
            const float sc = (g == 2) ? (-2.0f * L2E) : (-L2E);
            wsWH[seg * 256 + jj * 32 + rr] = sc * Whh[seg * 256 + (g * 8 + jj) * 8 + (jj ^ m)];
        }
        if (tid < 32) {
            const float sc = ((tid >> 3) == 2) ? (-2.0f * L2E) : (-L2E);
            wsBIAS[seg * 32 + tid] = sc * bW[seg * 32 + tid];
        }
    }
}

// ---------------- one bidirectional layer (both directions merged) ----------------
template<bool LAST>
__device__ __forceinline__ void run_layer(unsigned* __restrict__ XS,
                                          const unsigned* __restrict__ bfF,
                                          const unsigned* __restrict__ bfB,
                                          const float* __restrict__ whFg,
                                          const float* __restrict__ whBg,
                                          const float* __restrict__ biasF,
                                          const float* __restrict__ biasB,
                                          const float* __restrict__ Wout,
                                          float* __restrict__ g2w,
                                          float& accOut, int lane, int wid)
{
    const int r   = lane & 15;
    const int kb  = lane >> 4;
    const int grp = lane >> 3;
    const int j   = lane & 7;
    const int elg = wid * 8 + grp;

    // A-frag word address (swizzled): row r -> (tpar=r>>3, el=r&7); k-chunk kb
    const int AI0 = (((r >> 3) * 32 + wid * 8 + (r & 7)) << 4) + ((kb ^ (r & 3)) << 2);
    // G2 scatter base: [tpar(2)][unit(32)][el(8)]; lane writes els (kb&1)*4..+3 at unit r / 16+r
    const int sb0 = (kb >> 1) * 256 + r * 8 + (kb & 1) * 4;
    // G2 gather base: lane (grp,j) reads unit g*8+j, el grp
    const int gb  = j * 8 + grp;

    // ---- phase 1: both directions' projections -> registers (A loaded once) ----
    float gxF[4][10], gxB[4][10];
    {
        s16x8 BF0 = *(const s16x8*)&bfF[(0 * 64 + lane) * 4];
        s16x8 BF1 = *(const s16x8*)&bfF[(1 * 64 + lane) * 4];
        s16x8 BF2 = *(const s16x8*)&bfF[(2 * 64 + lane) * 4];
        s16x8 BF3 = *(const s16x8*)&bfF[(3 * 64 + lane) * 4];
        s16x8 BB0 = *(const s16x8*)&bfB[(0 * 64 + lane) * 4];
        s16x8 BB1 = *(const s16x8*)&bfB[(1 * 64 + lane) * 4];
        s16x8 BB2 = *(const s16x8*)&bfB[(2 * 64 + lane) * 4];
        s16x8 BB3 = *(const s16x8*)&bfB[(3 * 64 + lane) * 4];
        const float bf0 = biasF[r], bf1 = biasF[16 + r];
        const float bb0 = biasB[r], bb1 = biasB[16 + r];

        #pragma unroll
        for (int m = 0; m < 5; ++m) {
            s16x8 A = *(const s16x8*)&XS[AI0 + m * 1024];

            f32x4 a0 = {bf0, bf0, bf0, bf0}, a1 = {bf1, bf1, bf1, bf1};
            a0 = __builtin_amdgcn_mfma_f32_16x16x32_bf16(A, BF0, a0, 0, 0, 0);
            a0 = __builtin_amdgcn_mfma_f32_16x16x32_bf16(A, BF1, a0, 0, 0, 0);
            a1 = __builtin_amdgcn_mfma_f32_16x16x32_bf16(A, BF2, a1, 0, 0, 0);
            a1 = __builtin_amdgcn_mfma_f32_16x16x32_bf16(A, BF3, a1, 0, 0, 0);
            *(f32x4*)&g2w[sb0]       = a0;   // units 0..15
            *(f32x4*)&g2w[sb0 + 128] = a1;   // units 16..31
            #pragma unroll
            for (int t2 = 0; t2 < 2; ++t2)
                #pragma unroll
                for (int g = 0; g < 4; ++g)
                    gxF[g][2 * m + t2] = g2w[t2 * 256 + g * 64 + gb];

            f32x4 c0 = {bb0, bb0, bb0, bb0}, c1 = {bb1, bb1, bb1, bb1};
            c0 = __builtin_amdgcn_mfma_f32_16x16x32_bf16(A, BB0, c0, 0, 0, 0);
            c0 = __builtin_amdgcn_mfma_f32_16x16x32_bf16(A, BB1, c0, 0, 0, 0);
            c1 = __builtin_amdgcn_mfma_f32_16x16x32_bf16(A, BB2, c1, 0, 0, 0);
            c1 = __builtin_amdgcn_mfma_f32_16x16x32_bf16(A, BB3, c1, 0, 0, 0);
            *(f32x4*)&g2w[sb0]       = c0;
            *(f32x4*)&g2w[sb0 + 128] = c1;
            #pragma unroll
            for (int t2 = 0; t2 < 2; ++t2)
                #pragma unroll
                for (int g = 0; g < 4; ++g)
                    gxB[g][2 * m + t2] = g2w[t2 * 256 + g * 64 + gb];
        }
    }

    // ---- recurrent weights -> regs ----
    float whF[32], whB[32];
    #pragma unroll
    for (int q = 0; q < 8; ++q) {
        *(f32x4*)&whF[q * 4] = *(const f32x4*)&whFg[j * 32 + q * 4];
        *(f32x4*)&whB[q * 4] = *(const f32x4*)&whBg[j * 32 + q * 4];
    }

    float woutF[10], woutB[10];
    if (LAST) {
        #pragma unroll
        for (int t = 0; t < 10; ++t) {
            woutF[t] = Wout[t * 16 + j];
            woutB[t] = Wout[t * 16 + 8 + j];
        }
    }

    // ---- phase 2: both chains interleaved (independent -> 2x ILP) ----
    float hF = 0.0f, cF = 0.0f, hB = 0.0f, cB = 0.0f;
    #pragma unroll
    for (int tt = 0; tt < 10; ++tt) {
        const int sF = tt, sB = 9 - tt;
        float aF0 = gxF[0][sF], aF1 = gxF[1][sF], aF2 = gxF[2][sF], aF3 = gxF[3][sF];
        float aB0 = gxB[0][sB], aB1 = gxB[1][sB], aB2 = gxB[2][sB], aB3 = gxB[3][sB];
        if (tt > 0) {
            float hsF[8], hsB[8];
            hsF[0] = hF;
            hsF[1] = DPPX<DPP_X1>(hF);
            hsF[2] = DPPX<DPP_X2>(hF);
            hsF[3] = DPPX<DPP_X3>(hF);
            hsF[4] = SWZ(hF, 4);
            hsF[5] = DPPX<DPP_X1>(hsF[4]);
            hsF[6] = DPPX<DPP_X2>(hsF[4]);
            hsF[7] = DPPX<DPP_X7>(hF);
            hsB[0] = hB;
            hsB[1] = DPPX<DPP_X1>(hB);
            hsB[2] = DPPX<DPP_X2>(hB);
            hsB[3] = DPPX<DPP_X3>(hB);
            hsB[4] = SWZ(hB, 4);
            hsB[5] = DPPX<DPP_X1>(hsB[4]);
            hsB[6] = DPPX<DPP_X2>(hsB[4]);
            hsB[7] = DPPX<DPP_X7>(hB);
            #pragma unroll
            for (int m = 0; m < 8; ++m) {
                aF0 = fmaf(whF[m],      hsF[m], aF0);
                aB0 = fmaf(whB[m],      hsB[m], aB0);
                aF1 = fmaf(whF[8 + m],  hsF[m], aF1);
                aB1 = fmaf(whB[8 + m],  hsB[m], aB1);
                aF2 = fmaf(whF[16 + m], hsF[m], aF2);
                aB2 = fmaf(whB[16 + m], hsB[m], aB2);
                aF3 = fmaf(whF[24 + m], hsF[m], aF3);
                aB3 = fmaf(whB[24 + m], hsB[m], aB3);
            }
        }
        // weights prescaled: sigm = rcp(1+exp2(G)), tanh = 2*rcp(1+exp2(G2)) - 1
        const float igF = __builtin_amdgcn_rcpf(1.0f + __builtin_amdgcn_exp2f(aF0));
        const float fgF = __builtin_amdgcn_rcpf(1.0f + __builtin_amdgcn_exp2f(aF1));
        const float ggF = 2.0f * __builtin_amdgcn_rcpf(1.0f + __builtin_amdgcn_exp2f(aF2)) - 1.0f;
        const float ogF = __builtin_amdgcn_rcpf(1.0f + __builtin_amdgcn_exp2f(aF3));
        const float igB = __builtin_amdgcn_rcpf(1.0f + __builtin_amdgcn_exp2f(aB0));
        const float fgB = __builtin_amdgcn_rcpf(1.0f + __builtin_amdgcn_exp2f(aB1));
        const float ggB = 2.0f * __builtin_amdgcn_rcpf(1.0f + __builtin_amdgcn_exp2f(aB2)) - 1.0f;
        const float ogB = __builtin_amdgcn_rcpf(1.0f + __builtin_amdgcn_exp2f(aB3));
        cF = fmaf(fgF, cF, igF * ggF);
        cB = fmaf(fgB, cB, igB * ggB);
        const float ecF = __builtin_amdgcn_exp2f(-2.0f * L2E * cF);
        const float ecB = __builtin_amdgcn_exp2f(-2.0f * L2E * cB);
        hF = ogF * (2.0f * __builtin_amdgcn_rcpf(1.0f + ecF) - 1.0f);
        hB = ogB * (2.0f * __builtin_amdgcn_rcpf(1.0f + ecB) - 1.0f);

        if (LAST) {
            accOut += hF * woutF[sF] + hB * woutB[sB];
        } else {
            XS[XIDX(sF, elg, j)]     = pack_split(hF);   // in-place: old cols fully consumed
            XS[XIDX(sB, elg, 8 + j)] = pack_split(hB);
        }
    }
}

__global__ __launch_bounds__(TPB, 5)
void lstm_kernel(const float* __restrict__ x,
                 const unsigned* __restrict__ wsBF,
                 const float* __restrict__ wsWH,
                 const float* __restrict__ wsBIAS,
                 const float* __restrict__ Wout,
                 const float* __restrict__ bout,
                 float* __restrict__ out)
{
    __shared__ __align__(16) unsigned XA[5120];   // 20KB, single in-place buffer
    __shared__ __align__(16) float    G2[2048];   // 8KB, per-wave MFMA bounce (512 f32/wave)

    const int tid  = threadIdx.x;
    const int lane = tid & 63, wid = tid >> 6;

    // per-wave x staging (coalesced: wave reads its own 1200 contiguous floats)
    const float* xw = x + (size_t)blockIdx.x * 4800 + wid * 1200;
    for (int i = lane; i < 1200; i += 64) {
        int e = wid * 8 + i / 150, rr = i % 150;
        int c = rr / 50, r2 = rr % 50, t = r2 / 5, d = r2 % 5;
        XA[XIDX(t, e, c * 5 + d)] = pack_split(xw[i]);
    }
    for (int i = lane; i < 80; i += 64) {         // zero col 15 (layer-0 input is 15-dim)
        int t = i >> 3, e = wid * 8 + (i & 7);
        XA[XIDX(t, e, 15)] = 0u;
    }
    // NO __syncthreads anywhere: all LDS regions are wave-private, waves drift freely.

    float* g2w = &G2[wid * 512];
    float accOut = 0.0f;
    run_layer<false>(XA, wsBF + 0 * 4096, wsBF + 1 * 4096, wsWH + 0 * 256, wsWH + 1 * 256,
                     wsBIAS + 0 * 32, wsBIAS + 1 * 32, Wout, g2w, accOut, lane, wid);
    run_layer<false>(XA, wsBF + 2 * 4096, wsBF + 3 * 4096, wsWH + 2 * 256, wsWH + 3 * 256,
                     wsBIAS + 2 * 32, wsBIAS + 3 * 32, Wout, g2w, accOut, lane, wid);
    run_layer<true >(XA, wsBF + 4 * 4096, wsBF + 5 * 4096, wsWH + 4 * 256, wsWH + 5 * 256,
                     wsBIAS + 4 * 32, wsBIAS + 5 * 32, Wout, g2w, accOut, lane, wid);

    accOut += __shfl_xor(accOut, 1);
    accOut += __shfl_xor(accOut, 2);
    accOut += __shfl_xor(accOut, 4);
    if ((lane & 7) == 0)
        out[(size_t)blockIdx.x * 32 + wid * 8 + (lane >> 3)] = accOut + bout[0];
}

extern "C" void kernel_launch(void* const* d_in, const int* in_sizes, int n_in,
                              void* d_out, int out_size, void* d_ws, size_t ws_size,
                              hipStream_t stream) {
    const float* x        = (const float*)d_in[0];
    const float* Wih0     = (const float*)d_in[1];
    const float* Wih_rest = (const float*)d_in[2];
    const float* Whh      = (const float*)d_in[3];
    const float* b        = (const float*)d_in[4];
    const float* Wout     = (const float*)d_in[5];
    const float* bout     = (const float*)d_in[6];
    float* out = (float*)d_out;

    unsigned* wsBF   = (unsigned*)d_ws;                   // 6*4096 u32 = 96KB
    float*    wsWH   = (float*)d_ws + 6 * 4096;           // 6*256 f32
    float*    wsBIAS = (float*)d_ws + 6 * 4096 + 6 * 256; // 6*32 f32

    prep_kernel<<<1, TPB, 0, stream>>>(Wih0, Wih_rest, Whh, b, wsBF, wsWH, wsBIAS);

    const int nblocks = out_size / 32;  // 8192
    lstm_kernel<<<nblocks, TPB, 0, stream>>>(x, wsBF, wsWH, wsBIAS, Wout, bout, out);
}

// Round 9
// 317.430 us; speedup vs baseline: 2.6243x; 2.6243x over previous
//
#include <hip/hip_runtime.h>

#define TPB 256
#define L2E 1.44269504f

typedef float f32x4 __attribute__((ext_vector_type(4)));
typedef short s16x8 __attribute__((ext_vector_type(8)));

// lane->lane XOR shuffle within 32-lane halves (BitMode: xor<<10 | and 0x1F)
#define SWZ(v, m) __int_as_float(__builtin_amdgcn_ds_swizzle(__float_as_int(v), ((m) << 10) | 31))

// DPP cross-lane (VALU): quad_perm xor1/2/3, row_half_mirror = xor7 (within 8)
#define DPP_X1 0xB1
#define DPP_X2 0x4E
#define DPP_X3 0x1B
#define DPP_X7 0x141
template<int CTRL>
__device__ __forceinline__ float DPPX(float v) {
    int i = __float_as_int(v);
    return __int_as_float(__builtin_amdgcn_update_dpp(i, i, CTRL, 0xF, 0xF, false));
}

// exact two-term bf16 split packed into one u32: low16 = hi-part (even k), high16 = lo-part (odd k)
__device__ __forceinline__ unsigned pack_split(float v) {
    unsigned b  = __float_as_uint(v);
    unsigned hi = b >> 16;
    float    hf = __uint_as_float(b & 0xFFFF0000u);
    unsigned lob = __float_as_uint(v - hf) & 0xFFFF0000u;
    return lob | hi;
}

// X LDS layout: [t(10)][el(32)][16 words], col XOR-swizzled by ((el&3)<<2) in 4-word chunks
#define XIDX(t, e, col) ((((t) * 32 + (e)) << 4) | ((col) ^ (((e) & 3) << 2)))

// ---------------- prep kernel: build all segment weights once into d_ws ----------------
__global__ void prep_kernel(const float* __restrict__ Wih0,
                            const float* __restrict__ Wih_rest,
                            const float* __restrict__ Whh,
                            const float* __restrict__ bW,
                            unsigned* __restrict__ wsBF,
                            float* __restrict__ wsWH,
                            float* __restrict__ wsBIAS)
{
    const int tid = threadIdx.x;
    for (int seg = 0; seg < 6; ++seg) {
        const int l = seg >> 1, dir = seg & 1;
        {   // B-fragments: frag = nt*2+part; value = dup16(hi/lo of W_scaled[u][d])
            const int lane_ = tid & 63, part = (tid >> 6) & 1, nt = tid >> 7;
            const int u = nt * 16 + (lane_ & 15);
            const float sc = ((u >> 3) == 2) ? (-2.0f * L2E) : (-L2E);
            #pragma unroll
            for (int ip = 0; ip < 4; ++ip) {
                const int d = (lane_ >> 4) * 4 + ip;
                float w;
                if (l == 0) w = (d < 15) ? Wih0[dir * 480 + u * 15 + d] : 0.0f;
                else        w = Wih_rest[((l - 1) * 2 + dir) * 512 + u * 16 + d];
                w *= sc;
                unsigned b = __float_as_uint(w);
                unsigned v16;
                if (part == 0) v16 = b >> 16;
                else {
                    float hf = __uint_as_float(b & 0xFFFF0000u);
                    v16 = __float_as_uint(w - hf) >> 16;
                }
                wsBF[seg * 4096 + ((nt * 2 + part) * 64 + lane_) * 4 + ip] = v16 | (v16 << 16);
            }
        }
        {   // recurrent weights, pre-permuted for XOR exchange: wh[j][g*8+m] = s_g*Whh[g*8+j][j^m]
            const int jj = tid >> 5, rr = tid & 31, g = rr >> 3, m = rr & 7;
            const float sc = (g == 2) ? (-2.0f * L2E) : (-L2E);
            wsWH[seg * 256 + jj * 32 + rr] = sc * Whh[seg * 256 + (g * 8 + jj) * 8 + (jj ^ m)];
        }
        if (tid < 32) {
            const float sc = ((tid >> 3) == 2) ? (-2.0f * L2E) : (-L2E);
            wsBIAS[seg * 32 + tid] = sc * bW[seg * 32 + tid];
        }
    }
}

// ---------------- one bidirectional layer (both directions merged) ----------------
template<bool LAST>
__device__ __forceinline__ void run_layer(unsigned* __restrict__ XS,
                                          const unsigned* __restrict__ bfF,
                                          const unsigned* __restrict__ bfB,
                                          const float* __restrict__ whFg,
                                          const float* __restrict__ whBg,
                                          const float* __restrict__ biasF,
                                          const float* __restrict__ biasB,
                                          const float* __restrict__ Wout,
                                          float* __restrict__ g2F,
                                          float* __restrict__ g2B,
                                          float& accOut, int lane, int wid)
{
    const int r   = lane & 15;
    const int kb  = lane >> 4;
    const int grp = lane >> 3;
    const int j   = lane & 7;
    const int elg = wid * 8 + grp;

    // A-frag word address (swizzled): row r -> (tpar=r>>3, el=r&7); k-chunk kb
    const int AI0 = (((r >> 3) * 32 + wid * 8 + (r & 7)) << 4) + ((kb ^ (r & 3)) << 2);
    // G2 scatter base: [tpar(2)][unit(32)][el(8)]; lane writes els (kb&1)*4..+3 at unit r / 16+r
    const int sb0 = (kb >> 1) * 256 + r * 8 + (kb & 1) * 4;
    // G2 gather base: lane (grp,j) reads unit g*8+j, el grp
    const int gb  = j * 8 + grp;

    // ---- phase 1: both directions' projections -> registers (A loaded once) ----
    float gxF[4][10], gxB[4][10];
    {
        s16x8 BF0 = *(const s16x8*)&bfF[(0 * 64 + lane) * 4];
        s16x8 BF1 = *(const s16x8*)&bfF[(1 * 64 + lane) * 4];
        s16x8 BF2 = *(const s16x8*)&bfF[(2 * 64 + lane) * 4];
        s16x8 BF3 = *(const s16x8*)&bfF[(3 * 64 + lane) * 4];
        s16x8 BB0 = *(const s16x8*)&bfB[(0 * 64 + lane) * 4];
        s16x8 BB1 = *(const s16x8*)&bfB[(1 * 64 + lane) * 4];
        s16x8 BB2 = *(const s16x8*)&bfB[(2 * 64 + lane) * 4];
        s16x8 BB3 = *(const s16x8*)&bfB[(3 * 64 + lane) * 4];
        const float bf0 = biasF[r], bf1 = biasF[16 + r];
        const float bb0 = biasB[r], bb1 = biasB[16 + r];

        #pragma unroll
        for (int m = 0; m < 5; ++m) {
            s16x8 A = *(const s16x8*)&XS[AI0 + m * 1024];

            f32x4 a0 = {bf0, bf0, bf0, bf0}, a1 = {bf1, bf1, bf1, bf1};
            a0 = __builtin_amdgcn_mfma_f32_16x16x32_bf16(A, BF0, a0, 0, 0, 0);
            a0 = __builtin_amdgcn_mfma_f32_16x16x32_bf16(A, BF1, a0, 0, 0, 0);
            a1 = __builtin_amdgcn_mfma_f32_16x16x32_bf16(A, BF2, a1, 0, 0, 0);
            a1 = __builtin_amdgcn_mfma_f32_16x16x32_bf16(A, BF3, a1, 0, 0, 0);
            f32x4 c0 = {bb0, bb0, bb0, bb0}, c1 = {bb1, bb1, bb1, bb1};
            c0 = __builtin_amdgcn_mfma_f32_16x16x32_bf16(A, BB0, c0, 0, 0, 0);
            c0 = __builtin_amdgcn_mfma_f32_16x16x32_bf16(A, BB1, c0, 0, 0, 0);
            c1 = __builtin_amdgcn_mfma_f32_16x16x32_bf16(A, BB2, c1, 0, 0, 0);
            c1 = __builtin_amdgcn_mfma_f32_16x16x32_bf16(A, BB3, c1, 0, 0, 0);

            // disjoint F/B regions: F-reads only wait on F-writes (counted lgkmcnt),
            // B-writes still in flight underneath.
            *(f32x4*)&g2F[sb0]       = a0;   // units 0..15
            *(f32x4*)&g2F[sb0 + 128] = a1;   // units 16..31
            *(f32x4*)&g2B[sb0]       = c0;
            *(f32x4*)&g2B[sb0 + 128] = c1;
            #pragma unroll
            for (int t2 = 0; t2 < 2; ++t2)
                #pragma unroll
                for (int g = 0; g < 4; ++g)
                    gxF[g][2 * m + t2] = g2F[t2 * 256 + g * 64 + gb];
            #pragma unroll
            for (int t2 = 0; t2 < 2; ++t2)
                #pragma unroll
                for (int g = 0; g < 4; ++g)
                    gxB[g][2 * m + t2] = g2B[t2 * 256 + g * 64 + gb];
        }
    }

    // ---- recurrent weights -> regs ----
    float whF[32], whB[32];
    #pragma unroll
    for (int q = 0; q < 8; ++q) {
        *(f32x4*)&whF[q * 4] = *(const f32x4*)&whFg[j * 32 + q * 4];
        *(f32x4*)&whB[q * 4] = *(const f32x4*)&whBg[j * 32 + q * 4];
    }

    float woutF[10], woutB[10];
    if (LAST) {
        #pragma unroll
        for (int t = 0; t < 10; ++t) {
            woutF[t] = Wout[t * 16 + j];
            woutB[t] = Wout[t * 16 + 8 + j];
        }
    }

    // ---- phase 2: both chains interleaved (independent -> 2x ILP) ----
    float hF = 0.0f, cF = 0.0f, hB = 0.0f, cB = 0.0f;
    #pragma unroll
    for (int tt = 0; tt < 10; ++tt) {
        const int sF = tt, sB = 9 - tt;
        float aF0 = gxF[0][sF], aF1 = gxF[1][sF], aF2 = gxF[2][sF], aF3 = gxF[3][sF];
        float aB0 = gxB[0][sB], aB1 = gxB[1][sB], aB2 = gxB[2][sB], aB3 = gxB[3][sB];
        if (tt > 0) {
            float hsF[8], hsB[8];
            hsF[0] = hF;
            hsF[1] = DPPX<DPP_X1>(hF);
            hsF[2] = DPPX<DPP_X2>(hF);
            hsF[3] = DPPX<DPP_X3>(hF);
            hsF[4] = SWZ(hF, 4);
            hsF[5] = DPPX<DPP_X1>(hsF[4]);
            hsF[6] = DPPX<DPP_X2>(hsF[4]);
            hsF[7] = DPPX<DPP_X7>(hF);
            hsB[0] = hB;
            hsB[1] = DPPX<DPP_X1>(hB);
            hsB[2] = DPPX<DPP_X2>(hB);
            hsB[3] = DPPX<DPP_X3>(hB);
            hsB[4] = SWZ(hB, 4);
            hsB[5] = DPPX<DPP_X1>(hsB[4]);
            hsB[6] = DPPX<DPP_X2>(hsB[4]);
            hsB[7] = DPPX<DPP_X7>(hB);
            #pragma unroll
            for (int m = 0; m < 8; ++m) {
                aF0 = fmaf(whF[m],      hsF[m], aF0);
                aB0 = fmaf(whB[m],      hsB[m], aB0);
                aF1 = fmaf(whF[8 + m],  hsF[m], aF1);
                aB1 = fmaf(whB[8 + m],  hsB[m], aB1);
                aF2 = fmaf(whF[16 + m], hsF[m], aF2);
                aB2 = fmaf(whB[16 + m], hsB[m], aB2);
                aF3 = fmaf(whF[24 + m], hsF[m], aF3);
                aB3 = fmaf(whB[24 + m], hsB[m], aB3);
            }
        }
        // weights prescaled: sigm = rcp(1+exp2(G)), tanh = 2*rcp(1+exp2(G2)) - 1
        const float igF = __builtin_amdgcn_rcpf(1.0f + __builtin_amdgcn_exp2f(aF0));
        const float fgF = __builtin_amdgcn_rcpf(1.0f + __builtin_amdgcn_exp2f(aF1));
        const float ggF = 2.0f * __builtin_amdgcn_rcpf(1.0f + __builtin_amdgcn_exp2f(aF2)) - 1.0f;
        const float ogF = __builtin_amdgcn_rcpf(1.0f + __builtin_amdgcn_exp2f(aF3));
        const float igB = __builtin_amdgcn_rcpf(1.0f + __builtin_amdgcn_exp2f(aB0));
        const float fgB = __builtin_amdgcn_rcpf(1.0f + __builtin_amdgcn_exp2f(aB1));
        const float ggB = 2.0f * __builtin_amdgcn_rcpf(1.0f + __builtin_amdgcn_exp2f(aB2)) - 1.0f;
        const float ogB = __builtin_amdgcn_rcpf(1.0f + __builtin_amdgcn_exp2f(aB3));
        cF = fmaf(fgF, cF, igF * ggF);
        cB = fmaf(fgB, cB, igB * ggB);
        const float ecF = __builtin_amdgcn_exp2f(-2.0f * L2E * cF);
        const float ecB = __builtin_amdgcn_exp2f(-2.0f * L2E * cB);
        hF = ogF * (2.0f * __builtin_amdgcn_rcpf(1.0f + ecF) - 1.0f);
        hB = ogB * (2.0f * __builtin_amdgcn_rcpf(1.0f + ecB) - 1.0f);

        if (LAST) {
            accOut += hF * woutF[sF] + hB * woutB[sB];
        } else {
            XS[XIDX(sF, elg, j)]     = pack_split(hF);   // in-place: old cols fully consumed
            XS[XIDX(sB, elg, 8 + j)] = pack_split(hB);
        }
    }
}

__global__ __launch_bounds__(TPB, 3)
void lstm_kernel(const float* __restrict__ x,
                 const unsigned* __restrict__ wsBF,
                 const float* __restrict__ wsWH,
                 const float* __restrict__ wsBIAS,
                 const float* __restrict__ Wout,
                 const float* __restrict__ bout,
                 float* __restrict__ out)
{
    __shared__ __align__(16) unsigned XA[5120];   // 20KB, single in-place buffer
    __shared__ __align__(16) float    G2[4096];   // 16KB: per-wave F half (512) + B half (512)

    const int tid  = threadIdx.x;
    const int lane = tid & 63, wid = tid >> 6;

    // per-wave x staging (coalesced: wave reads its own 1200 contiguous floats)
    const float* xw = x + (size_t)blockIdx.x * 4800 + wid * 1200;
    for (int i = lane; i < 1200; i += 64) {
        int e = wid * 8 + i / 150, rr = i % 150;
        int c = rr / 50, r2 = rr % 50, t = r2 / 5, d = r2 % 5;
        XA[XIDX(t, e, c * 5 + d)] = pack_split(xw[i]);
    }
    for (int i = lane; i < 80; i += 64) {         // zero col 15 (layer-0 input is 15-dim)
        int t = i >> 3, e = wid * 8 + (i & 7);
        XA[XIDX(t, e, 15)] = 0u;
    }
    // NO __syncthreads anywhere: all LDS regions are wave-private, waves drift freely.

    float* g2F = &G2[wid * 1024];
    float* g2B = g2F + 512;
    float accOut = 0.0f;
    run_layer<false>(XA, wsBF + 0 * 4096, wsBF + 1 * 4096, wsWH + 0 * 256, wsWH + 1 * 256,
                     wsBIAS + 0 * 32, wsBIAS + 1 * 32, Wout, g2F, g2B, accOut, lane, wid);
    run_layer<false>(XA, wsBF + 2 * 4096, wsBF + 3 * 4096, wsWH + 2 * 256, wsWH + 3 * 256,
                     wsBIAS + 2 * 32, wsBIAS + 3 * 32, Wout, g2F, g2B, accOut, lane, wid);
    run_layer<true >(XA, wsBF + 4 * 4096, wsBF + 5 * 4096, wsWH + 4 * 256, wsWH + 5 * 256,
                     wsBIAS + 4 * 32, wsBIAS + 5 * 32, Wout, g2F, g2B, accOut, lane, wid);

    accOut += __shfl_xor(accOut, 1);
    accOut += __shfl_xor(accOut, 2);
    accOut += __shfl_xor(accOut, 4);
    if ((lane & 7) == 0)
        out[(size_t)blockIdx.x * 32 + wid * 8 + (lane >> 3)] = accOut + bout[0];
}

extern "C" void kernel_launch(void* const* d_in, const int* in_sizes, int n_in,
                              void* d_out, int out_size, void* d_ws, size_t ws_size,
                              hipStream_t stream) {
    const float* x        = (const float*)d_in[0];
    const float* Wih0     = (const float*)d_in[1];
    const float* Wih_rest = (const float*)d_in[2];
    const float* Whh      = (const float*)d_in[3];
    const float* b        = (const float*)d_in[4];
    const float* Wout     = (const float*)d_in[5];
    const float* bout     = (const float*)d_in[6];
    float* out = (float*)d_out;

    unsigned* wsBF   = (unsigned*)d_ws;                   // 6*4096 u32 = 96KB
    float*    wsWH   = (float*)d_ws + 6 * 4096;           // 6*256 f32
    float*    wsBIAS = (float*)d_ws + 6 * 4096 + 6 * 256; // 6*32 f32

    prep_kernel<<<1, TPB, 0, stream>>>(Wih0, Wih_rest, Whh, b, wsBF, wsWH, wsBIAS);

    const int nblocks = out_size / 32;  // 8192
    lstm_kernel<<<nblocks, TPB, 0, stream>>>(x, wsBF, wsWH, wsBIAS, Wout, bout, out);
}

// Round 10
// 305.806 us; speedup vs baseline: 2.7241x; 1.0380x over previous
//
#include <hip/hip_runtime.h>

#define TPB 256
#define L2E 1.44269504f

typedef float f32x4 __attribute__((ext_vector_type(4)));
typedef short s16x8 __attribute__((ext_vector_type(8)));

// lane->lane XOR shuffle within 32-lane halves (BitMode: xor<<10 | and 0x1F)
#define SWZ(v, m) __int_as_float(__builtin_amdgcn_ds_swizzle(__float_as_int(v), ((m) << 10) | 31))

// DPP cross-lane (VALU): quad_perm xor1/2/3, row_half_mirror = xor7 (within 8)
#define DPP_X1 0xB1
#define DPP_X2 0x4E
#define DPP_X3 0x1B
#define DPP_X7 0x141
template<int CTRL>
__device__ __forceinline__ float DPPX(float v) {
    int i = __float_as_int(v);
    return __int_as_float(__builtin_amdgcn_update_dpp(i, i, CTRL, 0xF, 0xF, false));
}

// exact two-term bf16 split packed into one u32: low16 = hi-part (even k), high16 = lo-part (odd k)
__device__ __forceinline__ unsigned pack_split(float v) {
    unsigned b  = __float_as_uint(v);
    unsigned hi = b >> 16;
    float    hf = __uint_as_float(b & 0xFFFF0000u);
    unsigned lob = __float_as_uint(v - hf) & 0xFFFF0000u;
    return lob | hi;
}

// X LDS layout: [t(10)][el(32)][16 words], col XOR-swizzled by ((el&3)<<2) in 4-word chunks
#define XIDX(t, e, col) ((((t) * 32 + (e)) << 4) | ((col) ^ (((e) & 3) << 2)))

// ---------------- prep kernel: build all segment weights once into d_ws ----------------
__global__ void prep_kernel(const float* __restrict__ Wih0,
                            const float* __restrict__ Wih_rest,
                            const float* __restrict__ Whh,
                            const float* __restrict__ bW,
                            unsigned* __restrict__ wsBF,
                            float* __restrict__ wsWH,
                            float* __restrict__ wsBIAS)
{
    const int tid = threadIdx.x;
    for (int seg = 0; seg < 6; ++seg) {
        const int l = seg >> 1, dir = seg & 1;
        {   // B-fragments: frag = nt*2+part; value = dup16(hi/lo of W_scaled[u][d])
            const int lane_ = tid & 63, part = (tid >> 6) & 1, nt = tid >> 7;
            const int u = nt * 16 + (lane_ & 15);
            const float sc = ((u >> 3) == 2) ? (-2.0f * L2E) : (-L2E);
            #pragma unroll
            for (int ip = 0; ip < 4; ++ip) {
                const int d = (lane_ >> 4) * 4 + ip;
                float w;
                if (l == 0) w = (d < 15) ? Wih0[dir * 480 + u * 15 + d] : 0.0f;
                else        w = Wih_rest[((l - 1) * 2 + dir) * 512 + u * 16 + d];
                w *= sc;
                unsigned b = __float_as_uint(w);
                unsigned v16;
                if (part == 0) v16 = b >> 16;
                else {
                    float hf = __uint_as_float(b & 0xFFFF0000u);
                    v16 = __float_as_uint(w - hf) >> 16;
                }
                wsBF[seg * 4096 + ((nt * 2 + part) * 64 + lane_) * 4 + ip] = v16 | (v16 << 16);
            }
        }
        {   // recurrent weights, pre-permuted for XOR exchange: wh[j][g*8+m] = s_g*Whh[g*8+j][j^m]
            const int jj = tid >> 5, rr = tid & 31, g = rr >> 3, m = rr & 7;
            const float sc = (g == 2) ? (-2.0f * L2E) : (-L2E);
            wsWH[seg * 256 + jj * 32 + rr] = sc * Whh[seg * 256 + (g * 8 + jj) * 8 + (jj ^ m)];
        }
        if (tid < 32) {
            const float sc = ((tid >> 3) == 2) ? (-2.0f * L2E) : (-L2E);
            wsBIAS[seg * 32 + tid] = sc * bW[seg * 32 + tid];
        }
    }
}

// one LSTM cell step for this lane's unit j; gates prescaled so exp2 is direct.
template<bool FIRST>
__device__ __forceinline__ void lstm_step(float a0, float a1, float a2, float a3,
                                          const float* __restrict__ wh,
                                          float& c, float& h)
{
    if (!FIRST) {
        float hs[8];
        hs[0] = h;
        hs[1] = DPPX<DPP_X1>(h);
        hs[2] = DPPX<DPP_X2>(h);
        hs[3] = DPPX<DPP_X3>(h);
        hs[4] = SWZ(h, 4);
        hs[5] = DPPX<DPP_X1>(hs[4]);
        hs[6] = DPPX<DPP_X2>(hs[4]);
        hs[7] = DPPX<DPP_X7>(h);
        #pragma unroll
        for (int m = 0; m < 8; ++m) {
            a0 = fmaf(wh[m],      hs[m], a0);
            a1 = fmaf(wh[8 + m],  hs[m], a1);
            a2 = fmaf(wh[16 + m], hs[m], a2);
            a3 = fmaf(wh[24 + m], hs[m], a3);
        }
    }
    const float ig = __builtin_amdgcn_rcpf(1.0f + __builtin_amdgcn_exp2f(a0));
    const float fg = __builtin_amdgcn_rcpf(1.0f + __builtin_amdgcn_exp2f(a1));
    const float gg = 2.0f * __builtin_amdgcn_rcpf(1.0f + __builtin_amdgcn_exp2f(a2)) - 1.0f;
    const float og = __builtin_amdgcn_rcpf(1.0f + __builtin_amdgcn_exp2f(a3));
    c = fmaf(fg, c, ig * gg);
    const float ec = __builtin_amdgcn_exp2f(-2.0f * L2E * c);
    h = og * (2.0f * __builtin_amdgcn_rcpf(1.0f + ec) - 1.0f);
}

// ---------------- one bidirectional layer: 3 passes, live-set <= ~115 regs ----------------
template<bool LAST>
__device__ __forceinline__ void run_layer(unsigned* __restrict__ XS,
                                          const unsigned* __restrict__ bfF,
                                          const unsigned* __restrict__ bfB,
                                          const float* __restrict__ whFg,
                                          const float* __restrict__ whBg,
                                          const float* __restrict__ biasF,
                                          const float* __restrict__ biasB,
                                          const float* __restrict__ Wout,
                                          float* __restrict__ g2w,
                                          float& accOut, int lane, int wid)
{
    const int r   = lane & 15;
    const int kb  = lane >> 4;
    const int grp = lane >> 3;
    const int j   = lane & 7;
    const int elg = wid * 8 + grp;

    const int AI0 = (((r >> 3) * 32 + wid * 8 + (r & 7)) << 4) + ((kb ^ (r & 3)) << 2);
    const int sb0 = (kb >> 1) * 256 + r * 8 + (kb & 1) * 4;
    const int gb  = j * 8 + grp;

    // ---- pass 0: backward-direction projection -> gxB registers ----
    float gxB[4][10];
    {
        s16x8 BB0 = *(const s16x8*)&bfB[(0 * 64 + lane) * 4];
        s16x8 BB1 = *(const s16x8*)&bfB[(1 * 64 + lane) * 4];
        s16x8 BB2 = *(const s16x8*)&bfB[(2 * 64 + lane) * 4];
        s16x8 BB3 = *(const s16x8*)&bfB[(3 * 64 + lane) * 4];
        const float bb0 = biasB[r], bb1 = biasB[16 + r];
        #pragma unroll
        for (int m = 0; m < 5; ++m) {
            s16x8 A = *(const s16x8*)&XS[AI0 + m * 1024];
            f32x4 c0 = {bb0, bb0, bb0, bb0}, c1 = {bb1, bb1, bb1, bb1};
            c0 = __builtin_amdgcn_mfma_f32_16x16x32_bf16(A, BB0, c0, 0, 0, 0);
            c0 = __builtin_amdgcn_mfma_f32_16x16x32_bf16(A, BB1, c0, 0, 0, 0);
            c1 = __builtin_amdgcn_mfma_f32_16x16x32_bf16(A, BB2, c1, 0, 0, 0);
            c1 = __builtin_amdgcn_mfma_f32_16x16x32_bf16(A, BB3, c1, 0, 0, 0);
            *(f32x4*)&g2w[sb0]       = c0;   // units 0..15
            *(f32x4*)&g2w[sb0 + 128] = c1;   // units 16..31
            #pragma unroll
            for (int t2 = 0; t2 < 2; ++t2)
                #pragma unroll
                for (int g = 0; g < 4; ++g)
                    gxB[g][2 * m + t2] = g2w[t2 * 256 + g * 64 + gb];
        }
    }

    // ---- pass 1: forward projection fused with forward chain (gxF never materialized) ----
    {
        s16x8 BF0 = *(const s16x8*)&bfF[(0 * 64 + lane) * 4];
        s16x8 BF1 = *(const s16x8*)&bfF[(1 * 64 + lane) * 4];
        s16x8 BF2 = *(const s16x8*)&bfF[(2 * 64 + lane) * 4];
        s16x8 BF3 = *(const s16x8*)&bfF[(3 * 64 + lane) * 4];
        const float bf0 = biasF[r], bf1 = biasF[16 + r];
        float whF[32];
        #pragma unroll
        for (int q = 0; q < 8; ++q)
            *(f32x4*)&whF[q * 4] = *(const f32x4*)&whFg[j * 32 + q * 4];

        float hF = 0.0f, cF = 0.0f;
        #pragma unroll
        for (int m = 0; m < 5; ++m) {
            s16x8 A = *(const s16x8*)&XS[AI0 + m * 1024];
            f32x4 a0 = {bf0, bf0, bf0, bf0}, a1 = {bf1, bf1, bf1, bf1};
            a0 = __builtin_amdgcn_mfma_f32_16x16x32_bf16(A, BF0, a0, 0, 0, 0);
            a0 = __builtin_amdgcn_mfma_f32_16x16x32_bf16(A, BF1, a0, 0, 0, 0);
            a1 = __builtin_amdgcn_mfma_f32_16x16x32_bf16(A, BF2, a1, 0, 0, 0);
            a1 = __builtin_amdgcn_mfma_f32_16x16x32_bf16(A, BF3, a1, 0, 0, 0);
            *(f32x4*)&g2w[sb0]       = a0;
            *(f32x4*)&g2w[sb0 + 128] = a1;
            float gf[4][2];
            #pragma unroll
            for (int t2 = 0; t2 < 2; ++t2)
                #pragma unroll
                for (int g = 0; g < 4; ++g)
                    gf[g][t2] = g2w[t2 * 256 + g * 64 + gb];

            // F-steps 2m and 2m+1 (in-place X write is safe: tile m's A-read already done,
            // later tiles read rows >= 2m+2; pass 0 consumed all original rows)
            if (m == 0) lstm_step<true >(gf[0][0], gf[1][0], gf[2][0], gf[3][0], whF, cF, hF);
            else        lstm_step<false>(gf[0][0], gf[1][0], gf[2][0], gf[3][0], whF, cF, hF);
            if (LAST) accOut += hF * Wout[(2 * m) * 16 + j];
            else      XS[XIDX(2 * m, elg, j)] = pack_split(hF);

            lstm_step<false>(gf[0][1], gf[1][1], gf[2][1], gf[3][1], whF, cF, hF);
            if (LAST) accOut += hF * Wout[(2 * m + 1) * 16 + j];
            else      XS[XIDX(2 * m + 1, elg, j)] = pack_split(hF);
        }
    }

    // ---- pass 2: backward chain from gxB registers ----
    {
        float whB[32];
        #pragma unroll
        for (int q = 0; q < 8; ++q)
            *(f32x4*)&whB[q * 4] = *(const f32x4*)&whBg[j * 32 + q * 4];

        float hB = 0.0f, cB = 0.0f;
        #pragma unroll
        for (int tt = 0; tt < 10; ++tt) {
            const int s = 9 - tt;
            if (tt == 0) lstm_step<true >(gxB[0][s], gxB[1][s], gxB[2][s], gxB[3][s], whB, cB, hB);
            else         lstm_step<false>(gxB[0][s], gxB[1][s], gxB[2][s], gxB[3][s], whB, cB, hB);
            if (LAST) accOut += hB * Wout[s * 16 + 8 + j];
            else      XS[XIDX(s, elg, 8 + j)] = pack_split(hB);
        }
    }
}

__global__ __launch_bounds__(TPB, 4)
void lstm_kernel(const float* __restrict__ x,
                 const unsigned* __restrict__ wsBF,
                 const float* __restrict__ wsWH,
                 const float* __restrict__ wsBIAS,
                 const float* __restrict__ Wout,
                 const float* __restrict__ bout,
                 float* __restrict__ out)
{
    __shared__ __align__(16) unsigned XA[5120];   // 20KB, single in-place buffer
    __shared__ __align__(16) float    G2[2048];   // 8KB: 512 f32 per wave

    const int tid  = threadIdx.x;
    const int lane = tid & 63, wid = tid >> 6;

    // per-wave x staging (coalesced: wave reads its own 1200 contiguous floats)
    const float* xw = x + (size_t)blockIdx.x * 4800 + wid * 1200;
    for (int i = lane; i < 1200; i += 64) {
        int e = wid * 8 + i / 150, rr = i % 150;
        int c = rr / 50, r2 = rr % 50, t = r2 / 5, d = r2 % 5;
        XA[XIDX(t, e, c * 5 + d)] = pack_split(xw[i]);
    }
    for (int i = lane; i < 80; i += 64) {         // zero col 15 (layer-0 input is 15-dim)
        int t = i >> 3, e = wid * 8 + (i & 7);
        XA[XIDX(t, e, 15)] = 0u;
    }
    // NO __syncthreads anywhere: all LDS regions are wave-private, waves drift freely.

    float* g2w = &G2[wid * 512];
    float accOut = 0.0f;
    run_layer<false>(XA, wsBF + 0 * 4096, wsBF + 1 * 4096, wsWH + 0 * 256, wsWH + 1 * 256,
                     wsBIAS + 0 * 32, wsBIAS + 1 * 32, Wout, g2w, accOut, lane, wid);
    run_layer<false>(XA, wsBF + 2 * 4096, wsBF + 3 * 4096, wsWH + 2 * 256, wsWH + 3 * 256,
                     wsBIAS + 2 * 32, wsBIAS + 3 * 32, Wout, g2w, accOut, lane, wid);
    run_layer<true >(XA, wsBF + 4 * 4096, wsBF + 5 * 4096, wsWH + 4 * 256, wsWH + 5 * 256,
                     wsBIAS + 4 * 32, wsBIAS + 5 * 32, Wout, g2w, accOut, lane, wid);

    accOut += __shfl_xor(accOut, 1);
    accOut += __shfl_xor(accOut, 2);
    accOut += __shfl_xor(accOut, 4);
    if ((lane & 7) == 0)
        out[(size_t)blockIdx.x * 32 + wid * 8 + (lane >> 3)] = accOut + bout[0];
}

extern "C" void kernel_launch(void* const* d_in, const int* in_sizes, int n_in,
                              void* d_out, int out_size, void* d_ws, size_t ws_size,
                              hipStream_t stream) {
    const float* x        = (const float*)d_in[0];
    const float* Wih0     = (const float*)d_in[1];
    const float* Wih_rest = (const float*)d_in[2];
    const float* Whh      = (const float*)d_in[3];
    const float* b        = (const float*)d_in[4];
    const float* Wout     = (const float*)d_in[5];
    const float* bout     = (const float*)d_in[6];
    float* out = (float*)d_out;

    unsigned* wsBF   = (unsigned*)d_ws;                   // 6*4096 u32 = 96KB
    float*    wsWH   = (float*)d_ws + 6 * 4096;           // 6*256 f32
    float*    wsBIAS = (float*)d_ws + 6 * 4096 + 6 * 256; // 6*32 f32

    prep_kernel<<<1, TPB, 0, stream>>>(Wih0, Wih_rest, Whh, b, wsBF, wsWH, wsBIAS);

    const int nblocks = out_size / 32;  // 8192
    lstm_kernel<<<nblocks, TPB, 0, stream>>>(x, wsBF, wsWH, wsBIAS, Wout, bout, out);
}

// Round 11
// 297.598 us; speedup vs baseline: 2.7992x; 1.0276x over previous
//
#include <hip/hip_runtime.h>

#define TPB 256
#define L2E 1.44269504f

typedef float f32x4 __attribute__((ext_vector_type(4)));
typedef short s16x8 __attribute__((ext_vector_type(8)));

// lane->lane XOR shuffle within 32-lane halves (BitMode: xor<<10 | and 0x1F)
#define SWZ(v, m) __int_as_float(__builtin_amdgcn_ds_swizzle(__float_as_int(v), ((m) << 10) | 31))

// DPP cross-lane (VALU): quad_perm xor1/2/3, row_half_mirror = xor7 (within 8)
#define DPP_X1 0xB1
#define DPP_X2 0x4E
#define DPP_X3 0x1B
#define DPP_X7 0x141
template<int CTRL>
__device__ __forceinline__ float DPPX(float v) {
    int i = __float_as_int(v);
    return __int_as_float(__builtin_amdgcn_update_dpp(i, i, CTRL, 0xF, 0xF, false));
}

// exact two-term bf16 split packed into one u32: low16 = hi-part (even k), high16 = lo-part (odd k)
__device__ __forceinline__ unsigned pack_split(float v) {
    unsigned b  = __float_as_uint(v);
    unsigned hi = b >> 16;
    float    hf = __uint_as_float(b & 0xFFFF0000u);
    unsigned lob = __float_as_uint(v - hf) & 0xFFFF0000u;
    return lob | hi;
}

// X LDS layout: [t(10)][el(32)][16 words], col XOR-swizzled by ((el&3)<<2) in 4-word chunks
#define XIDX(t, e, col) ((((t) * 32 + (e)) << 4) | ((col) ^ (((e) & 3) << 2)))

// ---------------- prep kernel: build all segment weights once into d_ws ----------------
__global__ void prep_kernel(const float* __restrict__ Wih0,
                            const float* __restrict__ Wih_rest,
                            const float* __restrict__ Whh,
                            const float* __restrict__ bW,
                            unsigned* __restrict__ wsBF,
                            float* __restrict__ wsWH,
                            float* __restrict__ wsBIAS)
{
    const int tid = threadIdx.x;
    for (int seg = 0; seg < 6; ++seg) {
        const int l = seg >> 1, dir = seg & 1;
        {   // B-fragments: frag = nt*2+part; value = dup16(hi/lo of W_scaled[u][d])
            const int lane_ = tid & 63, part = (tid >> 6) & 1, nt = tid >> 7;
            const int u = nt * 16 + (lane_ & 15);
            const float sc = ((u >> 3) == 2) ? (-2.0f * L2E) : (-L2E);
            #pragma unroll
            for (int ip = 0; ip < 4; ++ip) {
                const int d = (lane_ >> 4) * 4 + ip;
                float w;
                if (l == 0) w = (d < 15) ? Wih0[dir * 480 + u * 15 + d] : 0.0f;
                else        w = Wih_rest[((l - 1) * 2 + dir) * 512 + u * 16 + d];
                w *= sc;
                unsigned b = __float_as_uint(w);
                unsigned v16;
                if (part == 0) v16 = b >> 16;
                else {
                    float hf = __uint_as_float(b & 0xFFFF0000u);
                    v16 = __float_as_uint(w - hf) >> 16;
                }
                wsBF[seg * 4096 + ((nt * 2 + part) * 64 + lane_) * 4 + ip] = v16 | (v16 << 16);
            }
        }
        {   // recurrent weights, pre-permuted for XOR exchange: wh[j][g*8+m] = s_g*Whh[g*8+j][j^m]
            const int jj = tid >> 5, rr = tid & 31, g = rr >> 3, m = rr & 7;
            const float sc = (g == 2) ? (-2.0f * L2E) : (-L2E);
            wsWH[seg * 256 + jj * 32 + rr] = sc * Whh[seg * 256 + (g * 8 + jj) * 8 + (jj ^ m)];
        }
        if (tid < 32) {
            const float sc = ((tid >> 3) == 2) ? (-2.0f * L2E) : (-L2E);
            wsBIAS[seg * 32 + tid] = sc * bW[seg * 32 + tid];
        }
    }
}

// one LSTM cell step for this lane's unit j; gates prescaled so exp2 is direct.
template<bool FIRST>
__device__ __forceinline__ void lstm_step(float a0, float a1, float a2, float a3,
                                          const float* __restrict__ wh,
                                          float& c, float& h)
{
    if (!FIRST) {
        float hs[8];
        hs[0] = h;
        hs[1] = DPPX<DPP_X1>(h);
        hs[2] = DPPX<DPP_X2>(h);
        hs[3] = DPPX<DPP_X3>(h);
        hs[4] = SWZ(h, 4);
        hs[5] = DPPX<DPP_X1>(hs[4]);
        hs[6] = DPPX<DPP_X2>(hs[4]);
        hs[7] = DPPX<DPP_X7>(h);
        #pragma unroll
        for (int m = 0; m < 8; ++m) {
            a0 = fmaf(wh[m],      hs[m], a0);
            a1 = fmaf(wh[8 + m],  hs[m], a1);
            a2 = fmaf(wh[16 + m], hs[m], a2);
            a3 = fmaf(wh[24 + m], hs[m], a3);
        }
    }
    const float ig = __builtin_amdgcn_rcpf(1.0f + __builtin_amdgcn_exp2f(a0));
    const float fg = __builtin_amdgcn_rcpf(1.0f + __builtin_amdgcn_exp2f(a1));
    const float gg = 2.0f * __builtin_amdgcn_rcpf(1.0f + __builtin_amdgcn_exp2f(a2)) - 1.0f;
    const float og = __builtin_amdgcn_rcpf(1.0f + __builtin_amdgcn_exp2f(a3));
    c = fmaf(fg, c, ig * gg);
    const float ec = __builtin_amdgcn_exp2f(-2.0f * L2E * c);
    h = og * (2.0f * __builtin_amdgcn_rcpf(1.0f + ec) - 1.0f);
}

// ---------------- one direction of one layer, projection fused with the chain ----------------
// DIR=0: tiles m=0..4 ascending (t = 2m, 2m+1).  DIR=1: tiles m=4..0 descending (t = 2m+1, 2m).
// The chain consumes gate values in production order in both cases -> NO gx register array.
template<int DIR, bool LAST>
__device__ __forceinline__ void run_dir(const unsigned* __restrict__ XSin,
                                        unsigned* __restrict__ XSout,
                                        const unsigned* __restrict__ bf,
                                        const float* __restrict__ whg,
                                        const float* __restrict__ biasg,
                                        const float* __restrict__ Wout,
                                        float* __restrict__ g2w,
                                        float& accOut, int lane, int wid)
{
    const int r   = lane & 15;
    const int kb  = lane >> 4;
    const int grp = lane >> 3;
    const int j   = lane & 7;
    const int elg = wid * 8 + grp;

    const int AI0 = (((r >> 3) * 32 + wid * 8 + (r & 7)) << 4) + ((kb ^ (r & 3)) << 2);
    const int sb0 = (kb >> 1) * 256 + r * 8 + (kb & 1) * 4;
    const int gb  = j * 8 + grp;

    s16x8 B0 = *(const s16x8*)&bf[(0 * 64 + lane) * 4];
    s16x8 B1 = *(const s16x8*)&bf[(1 * 64 + lane) * 4];
    s16x8 B2 = *(const s16x8*)&bf[(2 * 64 + lane) * 4];
    s16x8 B3 = *(const s16x8*)&bf[(3 * 64 + lane) * 4];
    const float bs0 = biasg[r], bs1 = biasg[16 + r];

    float wh[32];
    #pragma unroll
    for (int q = 0; q < 8; ++q)
        *(f32x4*)&wh[q * 4] = *(const f32x4*)&whg[j * 32 + q * 4];

    float woutr[10];
    if (LAST) {
        #pragma unroll
        for (int t = 0; t < 10; ++t) woutr[t] = Wout[t * 16 + DIR * 8 + j];
    }

    float h = 0.0f, c = 0.0f;
    #pragma unroll
    for (int mi = 0; mi < 5; ++mi) {
        const int m = DIR ? (4 - mi) : mi;
        s16x8 A = *(const s16x8*)&XSin[AI0 + m * 1024];
        f32x4 a0 = {bs0, bs0, bs0, bs0}, a1 = {bs1, bs1, bs1, bs1};
        a0 = __builtin_amdgcn_mfma_f32_16x16x32_bf16(A, B0, a0, 0, 0, 0);
        a0 = __builtin_amdgcn_mfma_f32_16x16x32_bf16(A, B1, a0, 0, 0, 0);
        a1 = __builtin_amdgcn_mfma_f32_16x16x32_bf16(A, B2, a1, 0, 0, 0);
        a1 = __builtin_amdgcn_mfma_f32_16x16x32_bf16(A, B3, a1, 0, 0, 0);
        *(f32x4*)&g2w[sb0]       = a0;   // units 0..15
        *(f32x4*)&g2w[sb0 + 128] = a1;   // units 16..31
        float gf[4][2];
        #pragma unroll
        for (int t2 = 0; t2 < 2; ++t2)
            #pragma unroll
            for (int g = 0; g < 4; ++g)
                gf[g][t2] = g2w[t2 * 256 + g * 64 + gb];

        #pragma unroll
        for (int k = 0; k < 2; ++k) {
            const int t2 = DIR ? (1 - k) : k;      // consume in chain order
            const int s  = 2 * m + t2;
            if (mi == 0 && k == 0)
                lstm_step<true >(gf[0][t2], gf[1][t2], gf[2][t2], gf[3][t2], wh, c, h);
            else
                lstm_step<false>(gf[0][t2], gf[1][t2], gf[2][t2], gf[3][t2], wh, c, h);
            if (LAST) accOut += h * woutr[s];
            else      XSout[XIDX(s, elg, DIR * 8 + j)] = pack_split(h);
        }
    }
}

__global__ __launch_bounds__(TPB, 3)
void lstm_kernel(const float* __restrict__ x,
                 const unsigned* __restrict__ wsBF,
                 const float* __restrict__ wsWH,
                 const float* __restrict__ wsBIAS,
                 const float* __restrict__ Wout,
                 const float* __restrict__ bout,
                 float* __restrict__ out)
{
    __shared__ __align__(16) unsigned XA[5120];   // 20KB
    __shared__ __align__(16) unsigned XB[5120];   // 20KB
    __shared__ __align__(16) float    G2[2048];   // 8KB: 512 f32 per wave

    const int tid  = threadIdx.x;
    const int lane = tid & 63, wid = tid >> 6;

    // per-wave x staging (coalesced: wave reads its own 1200 contiguous floats)
    const float* xw = x + (size_t)blockIdx.x * 4800 + wid * 1200;
    for (int i = lane; i < 1200; i += 64) {
        int e = wid * 8 + i / 150, rr = i % 150;
        int cc = rr / 50, r2 = rr % 50, t = r2 / 5, d = r2 % 5;
        XA[XIDX(t, e, cc * 5 + d)] = pack_split(xw[i]);
    }
    for (int i = lane; i < 80; i += 64) {         // zero col 15 (layer-0 input is 15-dim)
        int t = i >> 3, e = wid * 8 + (i & 7);
        XA[XIDX(t, e, 15)] = 0u;
    }
    // NO __syncthreads anywhere: all LDS regions are wave-private, waves drift freely.

    float* g2w = &G2[wid * 512];
    float accOut = 0.0f;
    // layer 0: XA -> XB
    run_dir<0, false>(XA, XB, wsBF + 0 * 4096, wsWH + 0 * 256, wsBIAS + 0 * 32, Wout, g2w, accOut, lane, wid);
    run_dir<1, false>(XA, XB, wsBF + 1 * 4096, wsWH + 1 * 256, wsBIAS + 1 * 32, Wout, g2w, accOut, lane, wid);
    // layer 1: XB -> XA
    run_dir<0, false>(XB, XA, wsBF + 2 * 4096, wsWH + 2 * 256, wsBIAS + 2 * 32, Wout, g2w, accOut, lane, wid);
    run_dir<1, false>(XB, XA, wsBF + 3 * 4096, wsWH + 3 * 256, wsBIAS + 3 * 32, Wout, g2w, accOut, lane, wid);
    // layer 2: XA -> accOut
    run_dir<0, true >(XA, XB, wsBF + 4 * 4096, wsWH + 4 * 256, wsBIAS + 4 * 32, Wout, g2w, accOut, lane, wid);
    run_dir<1, true >(XA, XB, wsBF + 5 * 4096, wsWH + 5 * 256, wsBIAS + 5 * 32, Wout, g2w, accOut, lane, wid);

    accOut += __shfl_xor(accOut, 1);
    accOut += __shfl_xor(accOut, 2);
    accOut += __shfl_xor(accOut, 4);
    if ((lane & 7) == 0)
        out[(size_t)blockIdx.x * 32 + wid * 8 + (lane >> 3)] = accOut + bout[0];
}

extern "C" void kernel_launch(void* const* d_in, const int* in_sizes, int n_in,
                              void* d_out, int out_size, void* d_ws, size_t ws_size,
                              hipStream_t stream) {
    const float* x        = (const float*)d_in[0];
    const float* Wih0     = (const float*)d_in[1];
    const float* Wih_rest = (const float*)d_in[2];
    const float* Whh      = (const float*)d_in[3];
    const float* b        = (const float*)d_in[4];
    const float* Wout     = (const float*)d_in[5];
    const float* bout     = (const float*)d_in[6];
    float* out = (float*)d_out;

    unsigned* wsBF   = (unsigned*)d_ws;                   // 6*4096 u32 = 96KB
    float*    wsWH   = (float*)d_ws + 6 * 4096;           // 6*256 f32
    float*    wsBIAS = (float*)d_ws + 6 * 4096 + 6 * 256; // 6*32 f32

    prep_kernel<<<1, TPB, 0, stream>>>(Wih0, Wih_rest, Whh, b, wsBF, wsWH, wsBIAS);

    const int nblocks = out_size / 32;  // 8192
    lstm_kernel<<<nblocks, TPB, 0, stream>>>(x, wsBF, wsWH, wsBIAS, Wout, bout, out);
}